// Round 7
// baseline (199.016 us; speedup 1.0000x reference)
//
#include <hip/hip_runtime.h>
#include <math.h>

// Margin loss with distance-weighted sampling — expectation form.
// R11: no staging. Across R5/R9/R10, VALUBusy*dur == ~31us constant while
// wall ranged 77-103us: all stall, redistributed by barrier-convoy LDS
// pipelines. xb (2MB) is L2-resident (FETCH 8.4MB), and for 16x16x32
// MFMA both A and B fragments are contiguous 16B/lane reads of xb rows
// (lane=row/col, quad=k-slot) -- LDS was a pure cache, not a transpose.
// So: load af[4][4]/bfr[4][4] straight from global, zero staging, zero
// staging barriers, 64 register-operand MFMAs, LDS = 4KB (beta+combine).
// No min-waves bound (R7/R8 spill lesson); peak regs ~230 -> up to 8
// waves/SIMD. Keeps: det P[3][64][8192] fold + atomic fallback, R9's
// store-then-add cross-wave combine, ticket-fused final.

#define NROWS 8192
#define DDIM  128
#define NPAIRF 7.0f
#define BT 128
#define NTILE (NROWS / BT)                    // 64
#define NPAIRS (NTILE * (NTILE + 1) / 2)      // 2080
#define LW2_SHIFT 57.70780163555852f          // 40 / ln2

typedef short bf16x8 __attribute__((ext_vector_type(8)));   // 8 bf16 = 4 VGPRs
typedef float f32x4  __attribute__((ext_vector_type(4)));   // MFMA C/D

template <bool B> struct BoolK { static constexpr bool value = B; };

__device__ __forceinline__ unsigned short f2bf(float f) {
    unsigned int u = __float_as_uint(f);
    return (unsigned short)((u + 0x7fffu + ((u >> 16) & 1u)) >> 16);   // RNE
}

// Fused: zero accum+ticket+rowacc, fp32->bf16 convert.
__global__ void prep_kernel(const float* __restrict__ x, unsigned short* __restrict__ xb,
                            float* __restrict__ rowacc, float* __restrict__ accum) {
    int t = blockIdx.x * 256 + threadIdx.x;
    if (t < NROWS * 3) rowacc[t] = 0.0f;
    if (t < 3) accum[t] = 0.0f;               // [0] num, [1] cnt, [2] ticket
    int idx = t * 4;
    float4 v = *(const float4*)&x[idx];
    ushort4 h;
    h.x = f2bf(v.x); h.y = f2bf(v.y); h.z = f2bf(v.z); h.w = f2bf(v.w);
    *(ushort4*)&xb[idx] = h;
}

// One block per unordered tile pair (I <= J). 4 waves, 64x64 wave tiles.
// MFMA operands loaded as fragments directly from global (L2-resident).
// DET: deterministic store to P[3][NTILE][NROWS]; else atomics to rowacc.
template <bool DET>
__global__ __launch_bounds__(256) void gram_kernel(
        const unsigned short* __restrict__ xb,
        const float* __restrict__ beta, float* __restrict__ rowacc,
        float* __restrict__ P) {
    __shared__ float BetR[BT];                   // beta+0.2, rows
    __shared__ float BetC[BT];                   // beta+0.2, cols
    __shared__ float comb_rows[BT][3];           // 1.5 KB
    __shared__ float comb_cols[BT][3];           // 1.5 KB

    // decode blockIdx -> (I, J), I <= J  (row lengths 64, 63, ..., 1)
    int rem = blockIdx.x, I = 0;
    while (rem >= NTILE - I) { rem -= NTILE - I; ++I; }
    const int J = I + rem;
    const int row0 = I * BT, col0 = J * BT;

    const int tid = threadIdx.x;
    const int lane = tid & 63;
    const int wave = tid >> 6;                  // 0..3
    const int wy = wave >> 1, wx = wave & 1;
    const int l15 = lane & 15, quad = lane >> 4;

    // fragment loads straight from global: row r, dims (kc*4+quad)*8..+8
    bf16x8 af[4][4], bfr[4][4];
#pragma unroll
    for (int i = 0; i < 4; i++) {
        const bf16x8* abase =
            (const bf16x8*)&xb[(size_t)(row0 + wy * 64 + i * 16 + l15) * DDIM];
        const bf16x8* bbase =
            (const bf16x8*)&xb[(size_t)(col0 + wx * 64 + i * 16 + l15) * DDIM];
#pragma unroll
        for (int kc = 0; kc < 4; kc++) {
            af[i][kc] = abase[kc * 4 + quad];
            bfr[i][kc] = bbase[kc * 4 + quad];
        }
    }

    // beta -> LDS (visible after the post-MFMA barrier)
    if (tid < BT) BetR[tid] = beta[row0 + tid] + 0.2f;
    else          BetC[tid - BT] = beta[col0 + (tid - BT)] + 0.2f;

    f32x4 acc[4][4];
#pragma unroll
    for (int i = 0; i < 4; i++)
#pragma unroll
        for (int j = 0; j < 4; j++) acc[i][j] = (f32x4){0.f, 0.f, 0.f, 0.f};

#pragma unroll
    for (int kc = 0; kc < 4; kc++)
#pragma unroll
        for (int i = 0; i < 4; i++)
#pragma unroll
            for (int j = 0; j < 4; j++)
                acc[i][j] = __builtin_amdgcn_mfma_f32_16x16x32_bf16(
                    af[i][kc], bfr[j][kc], acc[i][j], 0, 0, 0);

    __syncthreads();                             // BetR/BetC ready

    // ---- epilogue: column-side operands ----
    float bpc4[4];
    int cloc4[4];
#pragma unroll
    for (int j = 0; j < 4; j++) {
        int cl = wx * 64 + j * 16 + l15;
        bpc4[j] = BetC[cl];
        cloc4[j] = cl >> 3;
    }

    float tc0[4], tc1[4], tc2[4];
#pragma unroll
    for (int k = 0; k < 4; k++) tc0[k] = tc1[k] = tc2[k] = 0.0f;

    // per-row sums land on owner lane l15 == i*4+reg (all 64 lanes own one)
    float r0 = 0.f, r1 = 0.f, r2 = 0.f;

    auto fold = [&](auto diag_c) {
        constexpr bool DIAG = decltype(diag_c)::value;
#pragma unroll
        for (int i = 0; i < 4; i++) {
#pragma unroll
            for (int reg = 0; reg < 4; reg++) {
                int rl = wy * 64 + i * 16 + quad * 4 + reg;
                float bpm = BetR[rl];
                int rloc = rl >> 3;
                float s0 = 0.f, s1 = 0.f, s2 = 0.f;
#pragma unroll
                for (int j = 0; j < 4; j++) {
                    float g = acc[i][j][reg];
                    float base = fmaf(-2.0f, g, 2.0f);         // sq == 1 exactly
                    float d = __builtin_amdgcn_sqrtf(fmaxf(base, 1e-8f));
                    float t = fmaxf(base, 0.25f);
                    float u = fmaf(-0.25f, t, 1.0f);
                    // w = 2^(-63*log2 t - 62.5*log2 u - 40/ln2) == e^(lw - 40)
                    float lw2 = fmaf(-63.0f, __builtin_amdgcn_logf(t),
                                fmaf(-62.5f, __builtin_amdgcn_logf(u), -LW2_SHIFT));
                    bool valid = t < 1.96f;
                    if (DIAG) valid = valid && (rloc != cloc4[j]);
                    float w = valid ? __builtin_amdgcn_exp2f(lw2) : 0.0f;
                    float nlr = fmaxf(bpm - d, 0.0f);
                    s0 += w;
                    s1 = fmaf(w, nlr, s1);
                    s2 += (nlr > 0.0f) ? w : 0.0f;
                    if (!DIAG) {
                        float nlc = fmaxf(bpc4[j] - d, 0.0f);
                        tc0[j] += w;
                        tc1[j] = fmaf(w, nlc, tc1[j]);
                        tc2[j] += (nlc > 0.0f) ? w : 0.0f;
                    }
                }
                // immediate reduce across the 16 column-lanes
#pragma unroll
                for (int off = 1; off < 16; off <<= 1) {
                    s0 += __shfl_xor(s0, off);
                    s1 += __shfl_xor(s1, off);
                    s2 += __shfl_xor(s2, off);
                }
                if (l15 == i * 4 + reg) { r0 = s0; r1 = s1; r2 = s2; }
            }
        }
    };
    if (I == J) fold(BoolK<true>{}); else fold(BoolK<false>{});

    const int rowl = wy * 64 + (l15 >> 2) * 16 + quad * 4 + (l15 & 3);

    // col fold: reduce across quad groups; lane quad==j keeps col j
    float c0 = 0.f, c1 = 0.f, c2 = 0.f;
#pragma unroll
    for (int j = 0; j < 4; j++) {
        float t0 = tc0[j], t1 = tc1[j], t2 = tc2[j];
        t0 += __shfl_xor(t0, 16); t1 += __shfl_xor(t1, 16); t2 += __shfl_xor(t2, 16);
        t0 += __shfl_xor(t0, 32); t1 += __shfl_xor(t1, 32); t2 += __shfl_xor(t2, 32);
        if (quad == j) { c0 = t0; c1 = t1; c2 = t2; }
    }
    const int coll = wx * 64 + quad * 16 + l15;

    // cross-wave combine: wx halves for rows, wy halves for cols
    if (wx == 0) {
        comb_rows[rowl][0] = r0; comb_rows[rowl][1] = r1; comb_rows[rowl][2] = r2;
    }
    if (wy == 0 && I != J) {
        comb_cols[coll][0] = c0; comb_cols[coll][1] = c1; comb_cols[coll][2] = c2;
    }
    __syncthreads();
    if (wx == 1) {
        float v0 = r0 + comb_rows[rowl][0];
        float v1 = r1 + comb_rows[rowl][1];
        float v2 = r2 + comb_rows[rowl][2];
        int rg = row0 + rowl;
        if (DET) {
            P[(0 * NTILE + J) * NROWS + rg] = v0;
            P[(1 * NTILE + J) * NROWS + rg] = v1;
            P[(2 * NTILE + J) * NROWS + rg] = v2;
        } else {
            atomicAdd(&rowacc[rg * 3 + 0], v0);
            atomicAdd(&rowacc[rg * 3 + 1], v1);
            atomicAdd(&rowacc[rg * 3 + 2], v2);
        }
    }
    if (wy == 1 && I != J) {
        float v0 = c0 + comb_cols[coll][0];
        float v1 = c1 + comb_cols[coll][1];
        float v2 = c2 + comb_cols[coll][2];
        int cg = col0 + coll;
        if (DET) {
            P[(0 * NTILE + I) * NROWS + cg] = v0;
            P[(1 * NTILE + I) * NROWS + cg] = v1;
            P[(2 * NTILE + I) * NROWS + cg] = v2;
        } else {
            atomicAdd(&rowacc[cg * 3 + 0], v0);
            atomicAdd(&rowacc[cg * 3 + 1], v1);
            atomicAdd(&rowacc[cg * 3 + 2], v2);
        }
    }
}

// 4 threads per row: in-block positive pairs + expectation terms; the
// last block (ticket) writes out[0] -- no separate writeout launch.
template <bool DET>
__global__ void final_kernel(const float* __restrict__ x, const float* __restrict__ beta,
                             const float* __restrict__ rowacc, const float* __restrict__ P,
                             float* __restrict__ accum, float* __restrict__ out) {
    int t = blockIdx.x * blockDim.x + threadIdx.x;
    int i = t >> 2;
    int pp = t & 3;
    float betai = beta[i];
    const float4* xi = (const float4*)&x[(size_t)i * DDIM];
    int b0 = i & ~7;
    float num = 0.f, cnt = 0.f, fb1 = 0.f, fb2 = 0.f;
#pragma unroll
    for (int q = 0; q < 2; q++) {
        int j = b0 + pp + q * 4;
        const float4* xj = (const float4*)&x[(size_t)j * DDIM];
        float d2 = 0.0f;
#pragma unroll
        for (int k = 0; k < DDIM / 4; k++) {
            float4 va = xi[k], vb = xj[k];
            float dx = va.x - vb.x, dy = va.y - vb.y;
            float dz = va.z - vb.z, dw = va.w - vb.w;
            d2 = fmaf(dx, dx, fmaf(dy, dy, fmaf(dz, dz, fmaf(dw, dw, d2))));
        }
        float d = __builtin_amdgcn_sqrtf(d2 + 1e-8f);
        float nl = fmaxf(betai - d + 0.2f, 0.0f);
        fb1 += nl;
        fb2 += (nl > 0.0f) ? 1.0f : 0.0f;
        if (j != i) {
            float pl = fmaxf(d - betai + 0.2f, 0.0f);
            num += pl;
            cnt += (pl > 0.0f) ? 1.0f : 0.0f;
        }
    }
    float a0 = 0.f, a1 = 0.f, a2 = 0.f;
    if (DET) {
#pragma unroll
        for (int k = 0; k < 16; k++) {
            int s = pp + k * 4;
            a0 += P[(0 * NTILE + s) * NROWS + i];
            a1 += P[(1 * NTILE + s) * NROWS + i];
            a2 += P[(2 * NTILE + s) * NROWS + i];
        }
    }
#pragma unroll
    for (int off = 1; off < 4; off <<= 1) {
        num += __shfl_xor(num, off); cnt += __shfl_xor(cnt, off);
        fb1 += __shfl_xor(fb1, off); fb2 += __shfl_xor(fb2, off);
        a0 += __shfl_xor(a0, off);  a1 += __shfl_xor(a1, off);
        a2 += __shfl_xor(a2, off);
    }
    if (pp == 0) {
        if (!DET) { a0 = rowacc[i * 3 + 0]; a1 = rowacc[i * 3 + 1]; a2 = rowacc[i * 3 + 2]; }
        if (a0 > 0.0f) {
            num += NPAIRF * a1 / a0;
            cnt += NPAIRF * a2 / a0;
        } else {
            // degenerate row: uniform over all n columns; cross-block nl are all 0
            num += NPAIRF * fb1 / (float)NROWS;
            cnt += NPAIRF * fb2 / (float)NROWS;
        }
    } else {
        num = 0.f; cnt = 0.f;   // row totals duplicated across pair-slots — keep one
    }
#pragma unroll
    for (int off = 4; off < 64; off <<= 1) {
        num += __shfl_xor(num, off);
        cnt += __shfl_xor(cnt, off);
    }
    if ((threadIdx.x & 63) == 0) {
        atomicAdd(&accum[0], num);
        atomicAdd(&accum[1], cnt);
    }
    __syncthreads();                 // all this block's atomics issued & drained
    if (threadIdx.x == 0) {
        __threadfence();             // make them visible device-wide
        unsigned int old = __float_as_uint(atomicAdd(&accum[2], 1.0f));
        if (old == __float_as_uint((float)(gridDim.x - 1))) {
            // last block: all other blocks' adds are fenced-visible
            float n2 = atomicAdd(&accum[0], 0.0f);
            float c2 = atomicAdd(&accum[1], 0.0f);
            out[0] = n2 / c2;
        }
    }
}

extern "C" void kernel_launch(void* const* d_in, const int* in_sizes, int n_in,
                              void* d_out, int out_size, void* d_ws, size_t ws_size,
                              hipStream_t stream) {
    const float* x = (const float*)d_in[0];
    const float* beta = (const float*)d_in[2];
    float* out = (float*)d_out;
    float* ws = (float*)d_ws;

    float* accum = ws;                                    // 64 floats ([2]=ticket)
    float* rowacc = ws + 64;                              // 8192*3
    float* P = rowacc + NROWS * 3;                        // 3*64*8192 = 1.57M floats

    const size_t p_floats = (size_t)3 * NTILE * NROWS;
    const size_t det_bytes = (64 + NROWS * 3 + p_floats) * 4
                           + (size_t)NROWS * DDIM * 2;
    const bool det = ws_size >= det_bytes;

    unsigned short* xb = det
        ? (unsigned short*)(P + p_floats)
        : (unsigned short*)(rowacc + NROWS * 3);

    prep_kernel<<<NROWS * DDIM / 1024, 256, 0, stream>>>(x, xb, rowacc, accum);
    if (det) {
        gram_kernel<true><<<NPAIRS, 256, 0, stream>>>(xb, beta, rowacc, P);
        final_kernel<true><<<NROWS * 4 / 512, 512, 0, stream>>>(x, beta, rowacc, P, accum, out);
    } else {
        gram_kernel<false><<<NPAIRS, 256, 0, stream>>>(xb, beta, rowacc, P);
        final_kernel<false><<<NROWS * 4 / 512, 512, 0, stream>>>(x, beta, rowacc, P, accum, out);
    }
}

// Round 8
// 151.669 us; speedup vs baseline: 1.3122x; 1.3122x over previous
//
#include <hip/hip_runtime.h>
#include <math.h>

// Margin loss with distance-weighted sampling — expectation form.
// R12: two-front round. (1) gram reverts to R5's exact measured-best
// structure (77.8us: 64KB single-shot staging, launch_bounds(256,2),
// atomic rowacc fold) -- every post-R5 restructure regressed; only
// deletion is the sq buffer (||x||^2 == 1 by construction). (2) The
// never-profiled ~81us non-gram tail is rebuilt: final_kernel goes to
// one thread per (anchor, block-member) pair (65536 thr, 256 blocks vs
// 128), 8-lane shfl row fold, and the 1-block writeout launch is fused
// in via ticket+fence. 3 launches total; P/DET machinery deleted.

#define NROWS 8192
#define DDIM  128
#define NPAIRF 7.0f
#define BT 128
#define NTILE (NROWS / BT)                    // 64
#define NPAIRS (NTILE * (NTILE + 1) / 2)      // 2080
#define LW2_SHIFT 57.70780163555852f          // 40 / ln2

typedef short bf16x8 __attribute__((ext_vector_type(8)));   // 8 bf16 = 4 VGPRs
typedef float f32x4  __attribute__((ext_vector_type(4)));   // MFMA C/D

template <bool B> struct BoolK { static constexpr bool value = B; };

__device__ __forceinline__ unsigned short f2bf(float f) {
    unsigned int u = __float_as_uint(f);
    return (unsigned short)((u + 0x7fffu + ((u >> 16) & 1u)) >> 16);   // RNE
}

// Fused: zero accum+ticket+rowacc, fp32->bf16 convert.
__global__ void prep_kernel(const float* __restrict__ x, unsigned short* __restrict__ xb,
                            float* __restrict__ rowacc, float* __restrict__ accum) {
    int t = blockIdx.x * 256 + threadIdx.x;
    if (t < NROWS * 3) rowacc[t] = 0.0f;
    if (t < 3) accum[t] = 0.0f;               // [0] num, [1] cnt, [2] ticket
    int idx = t * 4;
    float4 v = *(const float4*)&x[idx];
    ushort4 h;
    h.x = f2bf(v.x); h.y = f2bf(v.y); h.z = f2bf(v.z); h.w = f2bf(v.w);
    *(ushort4*)&xb[idx] = h;
}

// One block per unordered tile pair (I <= J). 4 waves, 64x64 wave tiles.
// R5 structure: 64KB single-shot XOR-swizzled staging, ts[] accumulator
// arrays, per-row 16-lane shfl fold, atomicAdd fold into rowacc.
__global__ __launch_bounds__(256, 2) void gram_kernel(
        const unsigned short* __restrict__ xb,
        const float* __restrict__ beta, float* __restrict__ rowacc) {
    __shared__ unsigned short Abuf[BT * DDIM];   // 32 KB
    __shared__ unsigned short Bbuf[BT * DDIM];   // 32 KB

    // decode blockIdx -> (I, J), I <= J  (row lengths 64, 63, ..., 1)
    int rem = blockIdx.x, I = 0;
    while (rem >= NTILE - I) { rem -= NTILE - I; ++I; }
    const int J = I + rem;
    const int row0 = I * BT, col0 = J * BT;

    const int tid = threadIdx.x;
    const int lane = tid & 63;
    const int wave = tid >> 6;
    const int wy = wave >> 1, wx = wave & 1;
    const int l15 = lane & 15, quad = lane >> 4;

    // stage both tiles; slot s -> row = s>>4, kb = s&15, phys = row*16 + (kb ^ (row&7))
    {
        uint4* dA = (uint4*)Abuf;
        uint4* dB = (uint4*)Bbuf;
#pragma unroll
        for (int t = 0; t < 8; t++) {
            int s = tid + t * 256;
            int row = s >> 4;
            int kb = s & 15;
            int phys = row * 16 + (kb ^ (row & 7));
            dA[phys] = *(const uint4*)&xb[(size_t)(row0 + row) * DDIM + kb * 8];
            dB[phys] = *(const uint4*)&xb[(size_t)(col0 + row) * DDIM + kb * 8];
        }
    }

    f32x4 acc[4][4];
#pragma unroll
    for (int i = 0; i < 4; i++)
#pragma unroll
        for (int j = 0; j < 4; j++) acc[i][j] = (f32x4){0.f, 0.f, 0.f, 0.f};

    __syncthreads();

#pragma unroll
    for (int kc = 0; kc < 4; kc++) {
        bf16x8 af[4], bfr[4];
#pragma unroll
        for (int i = 0; i < 4; i++) {
            int ra = wy * 64 + i * 16 + l15;
            int pa = (kc * 4 + quad) ^ (ra & 7);
            af[i] = *(const bf16x8*)&Abuf[(ra * 16 + pa) * 8];
            int rb = wx * 64 + i * 16 + l15;
            int pb = (kc * 4 + quad) ^ (rb & 7);
            bfr[i] = *(const bf16x8*)&Bbuf[(rb * 16 + pb) * 8];
        }
#pragma unroll
        for (int i = 0; i < 4; i++)
#pragma unroll
            for (int j = 0; j < 4; j++)
                acc[i][j] = __builtin_amdgcn_mfma_f32_16x16x32_bf16(
                    af[i], bfr[j], acc[i][j], 0, 0, 0);
    }

    // ---- epilogue: per-element shared math, two-sided fold ----
    float bpc4[4];
    int cloc4[4];
#pragma unroll
    for (int j = 0; j < 4; j++) {
        int cl = wx * 64 + j * 16 + l15;
        bpc4[j] = beta[col0 + cl] + 0.2f;
        cloc4[j] = cl >> 3;
    }
    float bpm16[16];
    int rloc16[16];
#pragma unroll
    for (int i = 0; i < 4; i++)
#pragma unroll
        for (int reg = 0; reg < 4; reg++) {
            int idx = i * 4 + reg;
            int rl = wy * 64 + i * 16 + quad * 4 + reg;
            bpm16[idx] = beta[row0 + rl] + 0.2f;
            rloc16[idx] = rl >> 3;
        }

    float ts0[16], ts1[16], ts2[16];
    float tc0[4], tc1[4], tc2[4];
#pragma unroll
    for (int k = 0; k < 16; k++) ts0[k] = ts1[k] = ts2[k] = 0.0f;
#pragma unroll
    for (int k = 0; k < 4; k++) tc0[k] = tc1[k] = tc2[k] = 0.0f;

    auto fold = [&](auto diag_c) {
        constexpr bool DIAG = decltype(diag_c)::value;
#pragma unroll
        for (int i = 0; i < 4; i++)
#pragma unroll
            for (int reg = 0; reg < 4; reg++) {
                const int idx = i * 4 + reg;
                const float bpm = bpm16[idx];
#pragma unroll
                for (int j = 0; j < 4; j++) {
                    float g = acc[i][j][reg];
                    float dist2 = fmaxf(fmaf(-2.0f, g, 2.0f), 0.0f);   // sq == 1
                    float d = __builtin_amdgcn_sqrtf(dist2 + 1e-8f);
                    float t = fmaxf(dist2, 0.25f);
                    float u = fmaf(-0.25f, t, 1.0f);
                    // w = 2^(-63*log2 t - 62.5*log2 u - 40/ln2) == e^(lw - 40)
                    float lw2 = fmaf(-63.0f, __builtin_amdgcn_logf(t),
                                fmaf(-62.5f, __builtin_amdgcn_logf(u), -LW2_SHIFT));
                    bool valid = t < 1.96f;
                    if (DIAG) valid = valid && (rloc16[idx] != cloc4[j]);
                    float w = valid ? __builtin_amdgcn_exp2f(lw2) : 0.0f;
                    float nlr = fmaxf(bpm - d, 0.0f);
                    ts0[idx] += w;
                    ts1[idx] = fmaf(w, nlr, ts1[idx]);
                    ts2[idx] += (nlr > 0.0f) ? w : 0.0f;
                    if (!DIAG) {
                        float nlc = fmaxf(bpc4[j] - d, 0.0f);
                        tc0[j] += w;
                        tc1[j] = fmaf(w, nlc, tc1[j]);
                        tc2[j] += (nlc > 0.0f) ? w : 0.0f;
                    }
                }
            }
    };
    if (I == J) fold(BoolK<true>{}); else fold(BoolK<false>{});

    // row fold: reduce the 16 column-lanes; lane l15==idx keeps its row's sums
    float r0 = 0.f, r1 = 0.f, r2 = 0.f;
#pragma unroll
    for (int idx = 0; idx < 16; idx++) {
        float t0 = ts0[idx], t1 = ts1[idx], t2 = ts2[idx];
#pragma unroll
        for (int off = 1; off < 16; off <<= 1) {
            t0 += __shfl_xor(t0, off);
            t1 += __shfl_xor(t1, off);
            t2 += __shfl_xor(t2, off);
        }
        if (l15 == idx) { r0 = t0; r1 = t1; r2 = t2; }
    }
    {
        int rg = row0 + wy * 64 + (l15 >> 2) * 16 + quad * 4 + (l15 & 3);
        atomicAdd(&rowacc[rg * 3 + 0], r0);
        atomicAdd(&rowacc[rg * 3 + 1], r1);
        atomicAdd(&rowacc[rg * 3 + 2], r2);
    }

    // col fold (off-diag only): reduce across the 4 quad groups; quad==j keeps col j
    if (I != J) {
        float c0 = 0.f, c1 = 0.f, c2 = 0.f;
#pragma unroll
        for (int j = 0; j < 4; j++) {
            float t0 = tc0[j], t1 = tc1[j], t2 = tc2[j];
            t0 += __shfl_xor(t0, 16); t1 += __shfl_xor(t1, 16); t2 += __shfl_xor(t2, 16);
            t0 += __shfl_xor(t0, 32); t1 += __shfl_xor(t1, 32); t2 += __shfl_xor(t2, 32);
            if (quad == j) { c0 = t0; c1 = t1; c2 = t2; }
        }
        int cg = col0 + wx * 64 + quad * 16 + l15;
        atomicAdd(&rowacc[cg * 3 + 0], c0);
        atomicAdd(&rowacc[cg * 3 + 1], c1);
        atomicAdd(&rowacc[cg * 3 + 2], c2);
    }
}

// One thread per (anchor i, block-member p): 65536 threads, 256 blocks.
// 8-lane shfl row fold; rowacc expectation terms on the row leader;
// ticket-fenced writeout fused in (no separate launch).
__global__ __launch_bounds__(256) void final_kernel(
        const float* __restrict__ x, const float* __restrict__ beta,
        const float* __restrict__ rowacc, float* __restrict__ accum,
        float* __restrict__ out) {
    int t = blockIdx.x * 256 + threadIdx.x;   // t = i*8 + p
    int i = t >> 3;
    int p = t & 7;
    int j = (i & ~7) + p;
    float betai = beta[i];
    const float4* xi = (const float4*)&x[(size_t)i * DDIM];
    const float4* xj = (const float4*)&x[(size_t)j * DDIM];
    float d2 = 0.0f;
#pragma unroll
    for (int k = 0; k < DDIM / 4; k++) {
        float4 va = xi[k], vb = xj[k];
        float dx = va.x - vb.x, dy = va.y - vb.y;
        float dz = va.z - vb.z, dw = va.w - vb.w;
        d2 = fmaf(dx, dx, fmaf(dy, dy, fmaf(dz, dz, fmaf(dw, dw, d2))));
    }
    float d = __builtin_amdgcn_sqrtf(d2 + 1e-8f);
    float nl = fmaxf(betai - d + 0.2f, 0.0f);
    float fb1 = nl;
    float fb2 = (nl > 0.0f) ? 1.0f : 0.0f;
    float num = 0.f, cnt = 0.f;
    if (j != i) {
        float pl = fmaxf(d - betai + 0.2f, 0.0f);
        num = pl;
        cnt = (pl > 0.0f) ? 1.0f : 0.0f;
    }
    // fold the 8 members of this row (lanes i*8 .. i*8+7 are contiguous)
#pragma unroll
    for (int off = 1; off < 8; off <<= 1) {
        num += __shfl_xor(num, off); cnt += __shfl_xor(cnt, off);
        fb1 += __shfl_xor(fb1, off); fb2 += __shfl_xor(fb2, off);
    }
    if (p == 0) {
        float a0 = rowacc[i * 3 + 0], a1 = rowacc[i * 3 + 1], a2 = rowacc[i * 3 + 2];
        if (a0 > 0.0f) {
            num += NPAIRF * a1 / a0;
            cnt += NPAIRF * a2 / a0;
        } else {
            // degenerate row: uniform over all n columns; cross-block nl are all 0
            num += NPAIRF * fb1 / (float)NROWS;
            cnt += NPAIRF * fb2 / (float)NROWS;
        }
    } else {
        num = 0.f; cnt = 0.f;   // row totals duplicated across the 8 lanes — keep one
    }
#pragma unroll
    for (int off = 8; off < 64; off <<= 1) {
        num += __shfl_xor(num, off);
        cnt += __shfl_xor(cnt, off);
    }
    __shared__ float sm[8];
    int wv = threadIdx.x >> 6, ln = threadIdx.x & 63;
    if (ln == 0) { sm[wv] = num; sm[4 + wv] = cnt; }
    __syncthreads();
    if (threadIdx.x == 0) {
        float n2 = 0.f, c2 = 0.f;
#pragma unroll
        for (int w = 0; w < 4; w++) { n2 += sm[w]; c2 += sm[4 + w]; }
        atomicAdd(&accum[0], n2);
        atomicAdd(&accum[1], c2);
        __threadfence();             // make them visible device-wide
        unsigned int old = __float_as_uint(atomicAdd(&accum[2], 1.0f));
        if (old == __float_as_uint((float)(gridDim.x - 1))) {
            // last block: all other blocks' adds are fenced-visible
            float nn = atomicAdd(&accum[0], 0.0f);
            float cc = atomicAdd(&accum[1], 0.0f);
            out[0] = nn / cc;
        }
    }
}

extern "C" void kernel_launch(void* const* d_in, const int* in_sizes, int n_in,
                              void* d_out, int out_size, void* d_ws, size_t ws_size,
                              hipStream_t stream) {
    const float* x = (const float*)d_in[0];
    const float* beta = (const float*)d_in[2];
    float* out = (float*)d_out;
    float* ws = (float*)d_ws;

    float* accum = ws;                                    // 64 floats ([2]=ticket)
    float* rowacc = ws + 64;                              // 8192*3
    unsigned short* xb = (unsigned short*)(rowacc + NROWS * 3);

    prep_kernel<<<NROWS * DDIM / 1024, 256, 0, stream>>>(x, xb, rowacc, accum);
    gram_kernel<<<NPAIRS, 256, 0, stream>>>(xb, beta, rowacc);
    final_kernel<<<NROWS * 8 / 256, 256, 0, stream>>>(x, beta, rowacc, accum, out);
}